// Round 1
// baseline (920.690 us; speedup 1.0000x reference)
//
#include <hip/hip_runtime.h>
#include <cmath>

#define B_SZ   8
#define H_DIM  5120
#define NHEAD  128
#define QLR_D  1536
#define ROPE_D 64
#define KVLR_D 512
#define KVLEN  8192
#define SCALE_F 0.07216878364870322f  // 192^-0.5

// ws layout (float offsets)
#define WS_CQ     ((size_t)0)          // 8*1536
#define WS_QPE    ((size_t)12288)      // 8*8192
#define WS_QNOPE  ((size_t)77824)      // 8*65536
#define WS_KPEROT ((size_t)602112)     // 8*8192*64
#define WS_SCORES ((size_t)4796416)    // 8*128*8192
#define WS_ATTN   ((size_t)13185024)   // 8*128*512
#define WS_PART   ((size_t)13709312)   // up to 128*8*5120 (21 MB), reused per stage

// ---------------- split-K GEMV: C[8,N] = A[8,K] @ B[K,N], partials per k-chunk ----
__global__ __launch_bounds__(256) void gemv8_splitk(
    const float* __restrict__ A, const float* __restrict__ B,
    float* __restrict__ part, int K, int N, int KC)
{
    const int n4 = (blockIdx.x * 256 + threadIdx.x) * 4;
    if (n4 >= N) return;
    const int k0 = blockIdx.y * KC;
    const int kend = min(k0 + KC, K);
    float acc[8][4] = {};
    const float* bp = B + (size_t)k0 * N + n4;
    #pragma unroll 4
    for (int k = k0; k < kend; ++k) {
        const float4 bv = *reinterpret_cast<const float4*>(bp);
        bp += N;
        #pragma unroll
        for (int m = 0; m < 8; ++m) {
            const float av = A[(size_t)m * K + k];   // wave-uniform -> scalar/broadcast
            acc[m][0] = fmaf(av, bv.x, acc[m][0]);
            acc[m][1] = fmaf(av, bv.y, acc[m][1]);
            acc[m][2] = fmaf(av, bv.z, acc[m][2]);
            acc[m][3] = fmaf(av, bv.w, acc[m][3]);
        }
    }
    float* pp = part + (size_t)blockIdx.y * 8 * N;
    #pragma unroll
    for (int m = 0; m < 8; ++m) {
        float4 o; o.x = acc[m][0]; o.y = acc[m][1]; o.z = acc[m][2]; o.w = acc[m][3];
        *reinterpret_cast<float4*>(pp + (size_t)m * N + n4) = o;
    }
}

// ---------------- plain partial reduce: out[i] = sum_s part[s*stride + i] ----------
__global__ __launch_bounds__(256) void reduce_plain(
    const float* __restrict__ part, float* __restrict__ out,
    int splits, size_t stride, size_t count)
{
    size_t i = (size_t)blockIdx.x * 256 + threadIdx.x;
    if (i >= count) return;
    float s = 0.f;
    for (int k = 0; k < splits; ++k) s += part[(size_t)k * stride + i];
    out[i] = s;
}

// ---------------- reduce partials of hidden@W_DQ, then RMSNorm rows ---------------
__global__ __launch_bounds__(256) void reduce_rmsnorm(
    const float* __restrict__ part, const float* __restrict__ w,
    float* __restrict__ cq, int splits)
{
    const int m = blockIdx.x;                 // 0..7
    __shared__ float ybuf[QLR_D];
    __shared__ float red[256];
    float ss = 0.f;
    for (int n = threadIdx.x; n < QLR_D; n += 256) {
        float y = 0.f;
        for (int s = 0; s < splits; ++s) y += part[((size_t)s * 8 + m) * QLR_D + n];
        ybuf[n] = y;
        ss += y * y;
    }
    red[threadIdx.x] = ss; __syncthreads();
    for (int st = 128; st > 0; st >>= 1) {
        if (threadIdx.x < st) red[threadIdx.x] += red[threadIdx.x + st];
        __syncthreads();
    }
    const float r = 1.0f / sqrtf(red[0] / (float)QLR_D + 1e-6f);
    for (int n = threadIdx.x; n < QLR_D; n += 256)
        cq[(size_t)m * QLR_D + n] = w[n] * ybuf[n] * r;
}

// ---------------- reduce partials of cq@W_QR, apply RoPE at pos = KVLEN-1 ---------
__global__ __launch_bounds__(256) void reduce_rope_qpe(
    const float* __restrict__ part, float* __restrict__ qpe, int splits)
{
    const int idx = blockIdx.x * 256 + threadIdx.x;    // 8*128*32 pairs
    if (idx >= B_SZ * NHEAD * 32) return;
    const int p = idx & 31, h = (idx >> 5) & (NHEAD - 1), m = idx >> 12;
    const int n0 = h * ROPE_D + 2 * p;
    const int N = NHEAD * ROPE_D;
    float x0 = 0.f, x1 = 0.f;
    for (int s = 0; s < splits; ++s) {
        const float* pp = part + ((size_t)s * 8 + m) * N + n0;
        x0 += pp[0]; x1 += pp[1];
    }
    const double inv = pow(10000.0, -(double)p / 32.0);
    const float ang = 8191.0f * (float)inv;            // mimic f32 angle quantization
    const double c = cos((double)ang), s = sin((double)ang);
    const size_t o = (size_t)m * N + n0;
    qpe[o]     = (float)((double)x0 * c - (double)x1 * s);
    qpe[o + 1] = (float)((double)x0 * s + (double)x1 * c);
}

// ---------------- RoPE the whole k_pe cache ---------------------------------------
__global__ __launch_bounds__(256) void rope_kpe_kernel(
    const float* __restrict__ kpe, float* __restrict__ out)
{
    const size_t idx = (size_t)blockIdx.x * 256 + threadIdx.x; // b*8192*32 pairs
    if (idx >= (size_t)B_SZ * KVLEN * 32) return;
    const int p = (int)(idx & 31);
    const int k = (int)((idx >> 5) & (KVLEN - 1));
    const int b = (int)(idx >> 18);
    const size_t base = ((size_t)b * KVLEN + k) * ROPE_D + 2 * p;
    const float x0 = kpe[base], x1 = kpe[base + 1];
    const double inv = pow(10000.0, -(double)p / 32.0);
    const float ang = (float)k * (float)inv;
    const double c = cos((double)ang), s = sin((double)ang);
    out[base]     = (float)((double)x0 * c - (double)x1 * s);
    out[base + 1] = (float)((double)x0 * s + (double)x1 * c);
}

// ---------------- scores[b,h,k] = SCALE*(qpe.kperot + qnope.ckv) ------------------
// per block: 128 heads x 128 keys, K=576 in steps of 8
__global__ __launch_bounds__(256) void scores_kernel(
    const float* __restrict__ qpe, const float* __restrict__ qnope,
    const float* __restrict__ kperot, const float* __restrict__ ckv,
    float* __restrict__ scores)
{
    const int b  = blockIdx.y;
    const int k0 = blockIdx.x * 128;
    __shared__ float As[8][128];   // [comp][head]
    __shared__ float Bs[8][128];   // [comp][key]
    const int tid = threadIdx.x;
    const int tx = tid & 15, ty = tid >> 4;
    const int rh = tid >> 1, half = tid & 1;
    float acc[8][8] = {};
    for (int c0 = 0; c0 < 576; c0 += 8) {
        const float* aps; const float* bps; int astr, bstr;
        if (c0 < 64) {
            aps = qpe + (size_t)b * (NHEAD * ROPE_D) + c0;              astr = ROPE_D;
            bps = kperot + ((size_t)b * KVLEN + k0) * ROPE_D + c0;      bstr = ROPE_D;
        } else {
            aps = qnope + (size_t)b * (NHEAD * KVLR_D) + (c0 - 64);     astr = KVLR_D;
            bps = ckv + ((size_t)b * KVLEN + k0) * KVLR_D + (c0 - 64);  bstr = KVLR_D;
        }
        const float4 av = *reinterpret_cast<const float4*>(aps + (size_t)rh * astr + half * 4);
        const float4 bv = *reinterpret_cast<const float4*>(bps + (size_t)rh * bstr + half * 4);
        __syncthreads();
        As[half*4+0][rh] = av.x; As[half*4+1][rh] = av.y;
        As[half*4+2][rh] = av.z; As[half*4+3][rh] = av.w;
        Bs[half*4+0][rh] = bv.x; Bs[half*4+1][rh] = bv.y;
        Bs[half*4+2][rh] = bv.z; Bs[half*4+3][rh] = bv.w;
        __syncthreads();
        #pragma unroll
        for (int cc = 0; cc < 8; ++cc) {
            float a[8], bb[8];
            #pragma unroll
            for (int j = 0; j < 8; ++j) a[j]  = As[cc][ty * 8 + j];
            #pragma unroll
            for (int j = 0; j < 8; ++j) bb[j] = Bs[cc][tx * 8 + j];
            #pragma unroll
            for (int i = 0; i < 8; ++i)
                #pragma unroll
                for (int j = 0; j < 8; ++j)
                    acc[i][j] = fmaf(a[i], bb[j], acc[i][j]);
        }
    }
    for (int i = 0; i < 8; ++i) {
        float* srow = scores + ((size_t)b * NHEAD + ty * 8 + i) * KVLEN + k0 + tx * 8;
        #pragma unroll
        for (int j = 0; j < 8; ++j) srow[j] = acc[i][j] * SCALE_F;
    }
}

// ---------------- row softmax over 8192, in place ---------------------------------
__global__ __launch_bounds__(256) void softmax_kernel(float* __restrict__ sc)
{
    float* p = sc + (size_t)blockIdx.x * KVLEN;
    const int tid = threadIdx.x;
    float v[32];
    float mx = -3.402823466e38f;
    #pragma unroll
    for (int i = 0; i < 32; ++i) { v[i] = p[i * 256 + tid]; mx = fmaxf(mx, v[i]); }
    #pragma unroll
    for (int off = 32; off >= 1; off >>= 1) mx = fmaxf(mx, __shfl_xor(mx, off, 64));
    __shared__ float red[8];
    if ((tid & 63) == 0) red[tid >> 6] = mx;
    __syncthreads();
    mx = fmaxf(fmaxf(red[0], red[1]), fmaxf(red[2], red[3]));
    float sum = 0.f;
    #pragma unroll
    for (int i = 0; i < 32; ++i) { v[i] = expf(v[i] - mx); sum += v[i]; }
    #pragma unroll
    for (int off = 32; off >= 1; off >>= 1) sum += __shfl_xor(sum, off, 64);
    if ((tid & 63) == 0) red[4 + (tid >> 6)] = sum;
    __syncthreads();
    sum = red[4] + red[5] + red[6] + red[7];
    const float inv = 1.0f / sum;
    #pragma unroll
    for (int i = 0; i < 32; ++i) p[i * 256 + tid] = v[i] * inv;
}

// ---------------- PV: part[ks,b,h,l] = sum_{k in chunk} probs[b,h,k]*ckv[b,k,l] ---
// block: 32 heads x 128 l, K-chunk 1024 in steps of 16
__global__ __launch_bounds__(256) void pv_kernel(
    const float* __restrict__ probs, const float* __restrict__ ckv,
    float* __restrict__ part)
{
    const int l0 = blockIdx.x * 128;
    const int h0 = blockIdx.y * 32;
    const int ks = blockIdx.z >> 3, b = blockIdx.z & 7;
    const int kbase = ks * 1024;
    __shared__ float As[16][33];   // [comp][head]
    __shared__ float Bs[16][128];  // [comp][l]
    const int tid = threadIdx.x;
    const int tx = tid & 31, ty = tid >> 5;
    float acc[4][4] = {};
    for (int kt = 0; kt < 1024; kt += 16) {
        const int kk = kbase + kt;
        float4 av = make_float4(0.f, 0.f, 0.f, 0.f);
        int hh = 0, q = 0;
        if (tid < 128) {
            hh = tid >> 2; q = tid & 3;
            av = *reinterpret_cast<const float4*>(
                probs + ((size_t)b * NHEAD + h0 + hh) * KVLEN + kk + q * 4);
        }
        const float* cb = ckv + ((size_t)b * KVLEN + kk) * KVLR_D + l0;
        const int cc0 = tid >> 5, lq = tid & 31;
        const float4 bv0 = *reinterpret_cast<const float4*>(cb + (size_t)cc0 * KVLR_D + lq * 4);
        const float4 bv1 = *reinterpret_cast<const float4*>(cb + (size_t)(cc0 + 8) * KVLR_D + lq * 4);
        __syncthreads();
        if (tid < 128) {
            As[q*4+0][hh] = av.x; As[q*4+1][hh] = av.y;
            As[q*4+2][hh] = av.z; As[q*4+3][hh] = av.w;
        }
        *reinterpret_cast<float4*>(&Bs[cc0][lq * 4])     = bv0;
        *reinterpret_cast<float4*>(&Bs[cc0 + 8][lq * 4]) = bv1;
        __syncthreads();
        #pragma unroll
        for (int cc = 0; cc < 16; ++cc) {
            float a[4], bb[4];
            #pragma unroll
            for (int j = 0; j < 4; ++j) a[j]  = As[cc][ty * 4 + j];
            #pragma unroll
            for (int j = 0; j < 4; ++j) bb[j] = Bs[cc][tx * 4 + j];
            #pragma unroll
            for (int i = 0; i < 4; ++i)
                #pragma unroll
                for (int j = 0; j < 4; ++j)
                    acc[i][j] = fmaf(a[i], bb[j], acc[i][j]);
        }
    }
    #pragma unroll
    for (int i = 0; i < 4; ++i) {
        float* op = part + (((size_t)ks * B_SZ + b) * NHEAD + h0 + ty * 4 + i) * KVLR_D
                    + l0 + tx * 4;
        #pragma unroll
        for (int j = 0; j < 4; ++j) op[j] = acc[i][j];
    }
}

extern "C" void kernel_launch(void* const* d_in, const int* in_sizes, int n_in,
                              void* d_out, int out_size, void* d_ws, size_t ws_size,
                              hipStream_t stream)
{
    const float* hidden  = (const float*)d_in[0];
    const float* ckv     = (const float*)d_in[1];
    const float* kpe     = (const float*)d_in[2];
    const float* W_DQ    = (const float*)d_in[3];
    const float* ln_w    = (const float*)d_in[4];
    const float* W_QR    = (const float*)d_in[5];
    const float* W_UQ_UK = (const float*)d_in[6];
    const float* W_UV_O  = (const float*)d_in[7];
    float* out = (float*)d_out;
    float* ws  = (float*)d_ws;

    float* cq     = ws + WS_CQ;
    float* qpe    = ws + WS_QPE;
    float* qnope  = ws + WS_QNOPE;
    float* kperot = ws + WS_KPEROT;
    float* scores = ws + WS_SCORES;
    float* attn   = ws + WS_ATTN;
    float* part   = ws + WS_PART;

    // 1. cQ = rmsnorm(hidden @ W_DQ)
    gemv8_splitk<<<dim3(2, 160), 256, 0, stream>>>(hidden, W_DQ, part, H_DIM, QLR_D, 32);
    reduce_rmsnorm<<<8, 256, 0, stream>>>(part, ln_w, cq, 160);
    // 2. q_pe = rope(cQ @ W_QR)
    gemv8_splitk<<<dim3(8, 32), 256, 0, stream>>>(cq, W_QR, part, QLR_D, NHEAD * ROPE_D, 48);
    reduce_rope_qpe<<<128, 256, 0, stream>>>(part, qpe, 32);
    // 3. q_nope = cQ @ W_UQ_UK
    gemv8_splitk<<<dim3(64, 8), 256, 0, stream>>>(cq, W_UQ_UK, part, QLR_D, NHEAD * KVLR_D, 192);
    reduce_plain<<<2048, 256, 0, stream>>>(part, qnope, 8, (size_t)8 * 65536, (size_t)8 * 65536);
    // 4. rope whole k_pe cache
    rope_kpe_kernel<<<8192, 256, 0, stream>>>(kpe, kperot);
    // 5. scores
    scores_kernel<<<dim3(64, 8), 256, 0, stream>>>(qpe, qnope, kperot, ckv, scores);
    // 6. softmax (in place -> probs)
    softmax_kernel<<<1024, 256, 0, stream>>>(scores);
    // 7. attn = probs @ ckv (split-k 8)
    pv_kernel<<<dim3(4, 4, 64), 256, 0, stream>>>(scores, ckv, part);
    reduce_plain<<<2048, 256, 0, stream>>>(part, attn, 8, (size_t)524288, (size_t)524288);
    // 8. out = attn @ W_UV_O
    gemv8_splitk<<<dim3(5, 128), 256, 0, stream>>>(attn, W_UV_O, part, NHEAD * KVLR_D, H_DIM, 512);
    reduce_plain<<<160, 256, 0, stream>>>(part, out, 128, (size_t)40960, (size_t)40960);
}

// Round 2
// 823.609 us; speedup vs baseline: 1.1179x; 1.1179x over previous
//
#include <hip/hip_runtime.h>
#include <cmath>

#define B_SZ   8
#define H_DIM  5120
#define NHEAD  128
#define QLR_D  1536
#define ROPE_D 64
#define KVLR_D 512
#define KVLEN  8192
#define SCALE_F 0.07216878364870322f  // 192^-0.5

typedef __attribute__((ext_vector_type(8))) short bf16x8;
typedef __attribute__((ext_vector_type(4))) float f32x4;

// ws layout (float offsets)
#define WS_CQ     ((size_t)0)          // 12288
#define WS_QPE    ((size_t)12288)      // 65536  [b][h][64]
#define WS_QNOPE  ((size_t)77824)      // 524288 [b][h][512]
#define WS_KPEROT ((size_t)602112)     // 4194304 [b][k][64]
#define WS_TRIG   ((size_t)4796416)    // 524288  [k][p]{cos,sin}
#define WS_QH     ((size_t)5320704)    // 294912 float-slots (589824 ushort) [b][h][576]
#define WS_QL     ((size_t)5615616)    // 294912
#define WS_SCORES ((size_t)5910528)    // 8388608 fp32 [b][h][8192]
#define WS_PH     ((size_t)14299136)   // 4194304 float-slots (8.4M ushort)
#define WS_PL     ((size_t)18493440)   // 4194304
#define WS_ATTN   ((size_t)22687744)   // 524288
#define WS_PART   ((size_t)23212032)   // up to 10.5M floats

// ---------- bf16 helpers ----------
__device__ inline unsigned short f2bf(float x) {
    unsigned int u = __float_as_uint(x);
    u += 0x7FFFu + ((u >> 16) & 1u);
    return (unsigned short)(u >> 16);
}
__device__ inline float bf2f(unsigned short h) {
    return __uint_as_float(((unsigned int)h) << 16);
}

// ---------------- split-K GEMV: C[8,N] = A[8,K] @ B[K,N] ----------------
__global__ __launch_bounds__(256) void gemv8_splitk(
    const float* __restrict__ A, const float* __restrict__ B,
    float* __restrict__ part, int K, int N, int KC)
{
    const int n4 = (blockIdx.x * 256 + threadIdx.x) * 4;
    if (n4 >= N) return;
    const int k0 = blockIdx.y * KC;
    const int kend = min(k0 + KC, K);
    float acc[8][4] = {};
    const float* bp = B + (size_t)k0 * N + n4;
    #pragma unroll 4
    for (int k = k0; k < kend; ++k) {
        const float4 bv = *reinterpret_cast<const float4*>(bp);
        bp += N;
        #pragma unroll
        for (int m = 0; m < 8; ++m) {
            const float av = A[(size_t)m * K + k];
            acc[m][0] = fmaf(av, bv.x, acc[m][0]);
            acc[m][1] = fmaf(av, bv.y, acc[m][1]);
            acc[m][2] = fmaf(av, bv.z, acc[m][2]);
            acc[m][3] = fmaf(av, bv.w, acc[m][3]);
        }
    }
    float* pp = part + (size_t)blockIdx.y * 8 * N;
    #pragma unroll
    for (int m = 0; m < 8; ++m) {
        float4 o; o.x = acc[m][0]; o.y = acc[m][1]; o.z = acc[m][2]; o.w = acc[m][3];
        *reinterpret_cast<float4*>(pp + (size_t)m * N + n4) = o;
    }
}

__global__ __launch_bounds__(256) void reduce_plain(
    const float* __restrict__ part, float* __restrict__ out,
    int splits, size_t stride, size_t count)
{
    size_t i = (size_t)blockIdx.x * 256 + threadIdx.x;
    if (i >= count) return;
    float s = 0.f;
    for (int k = 0; k < splits; ++k) s += part[(size_t)k * stride + i];
    out[i] = s;
}

__global__ __launch_bounds__(256) void reduce_rmsnorm(
    const float* __restrict__ part, const float* __restrict__ w,
    float* __restrict__ cq, int splits)
{
    const int m = blockIdx.x;
    __shared__ float ybuf[QLR_D];
    __shared__ float red[256];
    float ss = 0.f;
    for (int n = threadIdx.x; n < QLR_D; n += 256) {
        float y = 0.f;
        for (int s = 0; s < splits; ++s) y += part[((size_t)s * 8 + m) * QLR_D + n];
        ybuf[n] = y;
        ss += y * y;
    }
    red[threadIdx.x] = ss; __syncthreads();
    for (int st = 128; st > 0; st >>= 1) {
        if (threadIdx.x < st) red[threadIdx.x] += red[threadIdx.x + st];
        __syncthreads();
    }
    const float r = 1.0f / sqrtf(red[0] / (float)QLR_D + 1e-6f);
    for (int n = threadIdx.x; n < QLR_D; n += 256)
        cq[(size_t)m * QLR_D + n] = w[n] * ybuf[n] * r;
}

__global__ __launch_bounds__(256) void reduce_rope_qpe(
    const float* __restrict__ part, float* __restrict__ qpe, int splits)
{
    const int idx = blockIdx.x * 256 + threadIdx.x;
    if (idx >= B_SZ * NHEAD * 32) return;
    const int p = idx & 31, h = (idx >> 5) & (NHEAD - 1), m = idx >> 12;
    const int n0 = h * ROPE_D + 2 * p;
    const int N = NHEAD * ROPE_D;
    float x0 = 0.f, x1 = 0.f;
    for (int s = 0; s < splits; ++s) {
        const float* pp = part + ((size_t)s * 8 + m) * N + n0;
        x0 += pp[0]; x1 += pp[1];
    }
    const double inv = pow(10000.0, -(double)p / 32.0);
    const float ang = 8191.0f * (float)inv;
    const double c = cos((double)ang), s = sin((double)ang);
    const size_t o = (size_t)m * N + n0;
    qpe[o]     = (float)((double)x0 * c - (double)x1 * s);
    qpe[o + 1] = (float)((double)x0 * s + (double)x1 * c);
}

// ---------------- trig table: [k][p] cos/sin -------------------------------------
__global__ __launch_bounds__(256) void trig_table_kernel(float2* __restrict__ tab)
{
    const int idx = blockIdx.x * 256 + threadIdx.x;
    if (idx >= KVLEN * 32) return;
    const int k = idx >> 5, p = idx & 31;
    const double inv = pow(10000.0, -(double)p / 32.0);
    const float ang = (float)k * (float)inv;
    tab[idx] = make_float2((float)cos((double)ang), (float)sin((double)ang));
}

// ---------------- RoPE the k_pe cache via table ----------------------------------
__global__ __launch_bounds__(256) void rope_kpe_kernel(
    const float* __restrict__ kpe, const float2* __restrict__ tab,
    float* __restrict__ out)
{
    const size_t idx = (size_t)blockIdx.x * 256 + threadIdx.x;
    if (idx >= (size_t)B_SZ * KVLEN * 32) return;
    const int p = (int)(idx & 31);
    const int k = (int)((idx >> 5) & (KVLEN - 1));
    const size_t base = 2 * idx;  // ((b*KVLEN+k)*32 + p)*2 == b,k,2p layout
    const float x0 = kpe[base], x1 = kpe[base + 1];
    const float2 cs = tab[k * 32 + p];
    out[base]     = x0 * cs.x - x1 * cs.y;
    out[base + 1] = x0 * cs.y + x1 * cs.x;
}

// ---------------- build q_hi/q_lo bf16 [b][h][576] from qpe+qnope ----------------
__global__ __launch_bounds__(256) void convert_q_kernel(
    const float* __restrict__ qpe, const float* __restrict__ qnope,
    unsigned short* __restrict__ qh, unsigned short* __restrict__ ql)
{
    const int idx = blockIdx.x * 256 + threadIdx.x;   // (b*128+h)*576 + c
    if (idx >= B_SZ * NHEAD * 576) return;
    const int c = idx % 576, bh = idx / 576;
    float x;
    if (c < 64) x = qpe[(size_t)bh * 64 + c];
    else        x = qnope[(size_t)bh * 512 + (c - 64)];
    const unsigned short hi = f2bf(x);
    qh[idx] = hi;
    ql[idx] = f2bf(x - bf2f(hi));
}

// ---------------- scores via split-bf16 MFMA -------------------------------------
// block: 128 heads x 128 keys, grid (64 key-chunks, 8 b), 256 thr = 4 waves (2x2)
__global__ __launch_bounds__(256) void scores_mfma(
    const unsigned short* __restrict__ qh, const unsigned short* __restrict__ ql,
    const float* __restrict__ kperot, const float* __restrict__ ckv,
    float* __restrict__ scores)
{
    const int b = blockIdx.y;
    const int k0 = blockIdx.x * 128;
    __shared__ __align__(16) unsigned short kbuf[128][64];  // row=key, ch0-3 hi, ch4-7 lo, ch^=(row&7)
    const int tid = threadIdx.x, lane = tid & 63, w = tid >> 6;
    const int hbase = (w >> 1) * 64, kbw = (w & 1) * 64;
    const int skey = tid >> 1, shalf = tid & 1;
    f32x4 acc[4][4] = {};

    for (int c0 = 0; c0 < 576; c0 += 32) {
        // stage 128 keys x 32 comps: fp32 -> bf16 hi/lo
        const float* src;
        if (c0 < 64) src = kperot + ((size_t)(b * KVLEN + k0 + skey)) * 64 + c0 + shalf * 16;
        else         src = ckv    + ((size_t)(b * KVLEN + k0 + skey)) * 512 + (c0 - 64) + shalf * 16;
        float v[16];
        #pragma unroll
        for (int q = 0; q < 4; ++q) {
            const float4 f = *reinterpret_cast<const float4*>(src + q * 4);
            v[q*4+0] = f.x; v[q*4+1] = f.y; v[q*4+2] = f.z; v[q*4+3] = f.w;
        }
        unsigned short hi[16], lo[16];
        #pragma unroll
        for (int e = 0; e < 16; ++e) {
            hi[e] = f2bf(v[e]);
            lo[e] = f2bf(v[e] - bf2f(hi[e]));
        }
        // A frags from global (L2-resident q)
        bf16x8 a_hi[4], a_lo[4];
        #pragma unroll
        for (int hs = 0; hs < 4; ++hs) {
            const size_t qoff = ((size_t)(b * NHEAD + hbase + hs * 16 + (lane & 15))) * 576
                                + c0 + (lane >> 4) * 8;
            a_hi[hs] = *reinterpret_cast<const bf16x8*>(qh + qoff);
            a_lo[hs] = *reinterpret_cast<const bf16x8*>(ql + qoff);
        }
        __syncthreads();
        {
            bf16x8* rowp = reinterpret_cast<bf16x8*>(&kbuf[skey][0]);
            const int r7 = skey & 7;
            rowp[(shalf * 2 + 0) ^ r7] = *reinterpret_cast<bf16x8*>(&hi[0]);
            rowp[(shalf * 2 + 1) ^ r7] = *reinterpret_cast<bf16x8*>(&hi[8]);
            rowp[(4 + shalf * 2 + 0) ^ r7] = *reinterpret_cast<bf16x8*>(&lo[0]);
            rowp[(4 + shalf * 2 + 1) ^ r7] = *reinterpret_cast<bf16x8*>(&lo[8]);
        }
        __syncthreads();
        #pragma unroll
        for (int ks = 0; ks < 4; ++ks) {
            const int row = kbw + ks * 16 + (lane & 15);
            const bf16x8* rp = reinterpret_cast<const bf16x8*>(&kbuf[row][0]);
            const int r7 = row & 7;
            const bf16x8 b_hi = rp[(lane >> 4) ^ r7];
            const bf16x8 b_lo = rp[(4 + (lane >> 4)) ^ r7];
            #pragma unroll
            for (int hs = 0; hs < 4; ++hs) {
                acc[hs][ks] = __builtin_amdgcn_mfma_f32_16x16x32_bf16(a_hi[hs], b_hi, acc[hs][ks], 0, 0, 0);
                acc[hs][ks] = __builtin_amdgcn_mfma_f32_16x16x32_bf16(a_hi[hs], b_lo, acc[hs][ks], 0, 0, 0);
                acc[hs][ks] = __builtin_amdgcn_mfma_f32_16x16x32_bf16(a_lo[hs], b_hi, acc[hs][ks], 0, 0, 0);
            }
        }
    }
    // epilogue: C/D map col=lane&15 (key), row=(lane>>4)*4+reg (head)
    #pragma unroll
    for (int hs = 0; hs < 4; ++hs)
        #pragma unroll
        for (int ks = 0; ks < 4; ++ks)
            #pragma unroll
            for (int r = 0; r < 4; ++r) {
                const int head = hbase + hs * 16 + (lane >> 4) * 4 + r;
                const int key  = k0 + kbw + ks * 16 + (lane & 15);
                scores[((size_t)(b * NHEAD + head)) * KVLEN + key] = acc[hs][ks][r] * SCALE_F;
            }
}

// ---------------- row softmax over 8192 -> probs hi/lo bf16 ----------------------
__global__ __launch_bounds__(256) void softmax_kernel(
    const float* __restrict__ sc, unsigned short* __restrict__ ph,
    unsigned short* __restrict__ pl)
{
    const size_t row = (size_t)blockIdx.x * KVLEN;
    const float* p = sc + row;
    const int tid = threadIdx.x;
    float v[32];
    float mx = -3.402823466e38f;
    #pragma unroll
    for (int i = 0; i < 32; ++i) { v[i] = p[i * 256 + tid]; mx = fmaxf(mx, v[i]); }
    #pragma unroll
    for (int off = 32; off >= 1; off >>= 1) mx = fmaxf(mx, __shfl_xor(mx, off, 64));
    __shared__ float red[8];
    if ((tid & 63) == 0) red[tid >> 6] = mx;
    __syncthreads();
    mx = fmaxf(fmaxf(red[0], red[1]), fmaxf(red[2], red[3]));
    float sum = 0.f;
    #pragma unroll
    for (int i = 0; i < 32; ++i) { v[i] = expf(v[i] - mx); sum += v[i]; }
    #pragma unroll
    for (int off = 32; off >= 1; off >>= 1) sum += __shfl_xor(sum, off, 64);
    if ((tid & 63) == 0) red[4 + (tid >> 6)] = sum;
    __syncthreads();
    sum = red[4] + red[5] + red[6] + red[7];
    const float inv = 1.0f / sum;
    #pragma unroll
    for (int i = 0; i < 32; ++i) {
        const float pr = v[i] * inv;
        const unsigned short hi = f2bf(pr);
        ph[row + i * 256 + tid] = hi;
        pl[row + i * 256 + tid] = f2bf(pr - bf2f(hi));
    }
}

// ---------------- PV via split-bf16 MFMA -----------------------------------------
// block: 128 heads x 128 l, keys chunk 1024; grid (4 l-tiles, 8 ks, 8 b)
__global__ __launch_bounds__(256) void pv_mfma(
    const unsigned short* __restrict__ ph, const unsigned short* __restrict__ pl,
    const float* __restrict__ ckv, float* __restrict__ part)
{
    const int lt = blockIdx.x, ks = blockIdx.y, b = blockIdx.z;
    const int l0 = lt * 128;
    __shared__ __align__(16) unsigned short vbuf[128][64];  // row=l, ch0-3 hi(kk), ch4-7 lo, ch^=(row&7)
    const int tid = threadIdx.x, lane = tid & 63, w = tid >> 6;
    const int hbase = (w >> 1) * 64, lbw = (w & 1) * 64;
    const int sl = tid & 127, skb = (tid >> 7) * 16;
    f32x4 acc[4][4] = {};

    const int kstart = ks * 1024;
    for (int kk0 = kstart; kk0 < kstart + 1024; kk0 += 32) {
        // stage ckv[kk0..+32][l0..+128] transposed -> vbuf[l][kk] hi/lo
        float v[16];
        #pragma unroll
        for (int e = 0; e < 16; ++e)
            v[e] = ckv[((size_t)(b * KVLEN + kk0 + skb + e)) * 512 + l0 + sl];
        unsigned short hi[16], lo[16];
        #pragma unroll
        for (int e = 0; e < 16; ++e) {
            hi[e] = f2bf(v[e]);
            lo[e] = f2bf(v[e] - bf2f(hi[e]));
        }
        // A frags (probs) from global
        bf16x8 a_hi[4], a_lo[4];
        #pragma unroll
        for (int hs = 0; hs < 4; ++hs) {
            const size_t poff = ((size_t)(b * NHEAD + hbase + hs * 16 + (lane & 15))) * KVLEN
                                + kk0 + (lane >> 4) * 8;
            a_hi[hs] = *reinterpret_cast<const bf16x8*>(ph + poff);
            a_lo[hs] = *reinterpret_cast<const bf16x8*>(pl + poff);
        }
        __syncthreads();
        {
            bf16x8* rowp = reinterpret_cast<bf16x8*>(&vbuf[sl][0]);
            const int r7 = sl & 7;
            const int cb = (tid >> 7) * 2;
            rowp[(cb + 0) ^ r7] = *reinterpret_cast<bf16x8*>(&hi[0]);
            rowp[(cb + 1) ^ r7] = *reinterpret_cast<bf16x8*>(&hi[8]);
            rowp[(4 + cb + 0) ^ r7] = *reinterpret_cast<bf16x8*>(&lo[0]);
            rowp[(4 + cb + 1) ^ r7] = *reinterpret_cast<bf16x8*>(&lo[8]);
        }
        __syncthreads();
        #pragma unroll
        for (int ls = 0; ls < 4; ++ls) {
            const int row = lbw + ls * 16 + (lane & 15);
            const bf16x8* rp = reinterpret_cast<const bf16x8*>(&vbuf[row][0]);
            const int r7 = row & 7;
            const bf16x8 v_hi = rp[(lane >> 4) ^ r7];
            const bf16x8 v_lo = rp[(4 + (lane >> 4)) ^ r7];
            #pragma unroll
            for (int hs = 0; hs < 4; ++hs) {
                acc[hs][ls] = __builtin_amdgcn_mfma_f32_16x16x32_bf16(a_hi[hs], v_hi, acc[hs][ls], 0, 0, 0);
                acc[hs][ls] = __builtin_amdgcn_mfma_f32_16x16x32_bf16(a_hi[hs], v_lo, acc[hs][ls], 0, 0, 0);
                acc[hs][ls] = __builtin_amdgcn_mfma_f32_16x16x32_bf16(a_lo[hs], v_hi, acc[hs][ls], 0, 0, 0);
            }
        }
    }
    #pragma unroll
    for (int hs = 0; hs < 4; ++hs)
        #pragma unroll
        for (int ls = 0; ls < 4; ++ls)
            #pragma unroll
            for (int r = 0; r < 4; ++r) {
                const int head = hbase + hs * 16 + (lane >> 4) * 4 + r;
                const int l    = l0 + lbw + ls * 16 + (lane & 15);
                part[(((size_t)ks * B_SZ + b) * NHEAD + head) * KVLR_D + l] = acc[hs][ls][r];
            }
}

extern "C" void kernel_launch(void* const* d_in, const int* in_sizes, int n_in,
                              void* d_out, int out_size, void* d_ws, size_t ws_size,
                              hipStream_t stream)
{
    const float* hidden  = (const float*)d_in[0];
    const float* ckv     = (const float*)d_in[1];
    const float* kpe     = (const float*)d_in[2];
    const float* W_DQ    = (const float*)d_in[3];
    const float* ln_w    = (const float*)d_in[4];
    const float* W_QR    = (const float*)d_in[5];
    const float* W_UQ_UK = (const float*)d_in[6];
    const float* W_UV_O  = (const float*)d_in[7];
    float* out = (float*)d_out;
    float* ws  = (float*)d_ws;

    float* cq     = ws + WS_CQ;
    float* qpe    = ws + WS_QPE;
    float* qnope  = ws + WS_QNOPE;
    float* kperot = ws + WS_KPEROT;
    float2* trig  = (float2*)(ws + WS_TRIG);
    unsigned short* qh = (unsigned short*)(ws + WS_QH);
    unsigned short* ql = (unsigned short*)(ws + WS_QL);
    float* scores = ws + WS_SCORES;
    unsigned short* prh = (unsigned short*)(ws + WS_PH);
    unsigned short* prl = (unsigned short*)(ws + WS_PL);
    float* attn   = ws + WS_ATTN;
    float* part   = ws + WS_PART;

    // 1. cQ = rmsnorm(hidden @ W_DQ)
    gemv8_splitk<<<dim3(2, 160), 256, 0, stream>>>(hidden, W_DQ, part, H_DIM, QLR_D, 32);
    reduce_rmsnorm<<<8, 256, 0, stream>>>(part, ln_w, cq, 160);
    // 2. q_pe = rope(cQ @ W_QR)
    gemv8_splitk<<<dim3(8, 32), 256, 0, stream>>>(cq, W_QR, part, QLR_D, NHEAD * ROPE_D, 48);
    reduce_rope_qpe<<<128, 256, 0, stream>>>(part, qpe, 32);
    // 3. q_nope = cQ @ W_UQ_UK
    gemv8_splitk<<<dim3(64, 8), 256, 0, stream>>>(cq, W_UQ_UK, part, QLR_D, NHEAD * KVLR_D, 192);
    reduce_plain<<<2048, 256, 0, stream>>>(part, qnope, 8, (size_t)524288, (size_t)524288);
    // 4. q -> bf16 hi/lo [b][h][576]
    convert_q_kernel<<<2304, 256, 0, stream>>>(qpe, qnope, qh, ql);
    // 5. trig table + rope k_pe
    trig_table_kernel<<<1024, 256, 0, stream>>>(trig);
    rope_kpe_kernel<<<8192, 256, 0, stream>>>(kpe, trig, kperot);
    // 6. scores (split-bf16 MFMA)
    scores_mfma<<<dim3(64, 8), 256, 0, stream>>>(qh, ql, kperot, ckv, scores);
    // 7. softmax -> probs hi/lo bf16
    softmax_kernel<<<1024, 256, 0, stream>>>(scores, prh, prl);
    // 8. attn = probs @ ckv (split-bf16 MFMA, split-K 8)
    pv_mfma<<<dim3(4, 8, 8), 256, 0, stream>>>(prh, prl, ckv, part);
    reduce_plain<<<2048, 256, 0, stream>>>(part, attn, 8, (size_t)524288, (size_t)524288);
    // 9. out = attn @ W_UV_O
    gemv8_splitk<<<dim3(5, 256), 256, 0, stream>>>(attn, W_UV_O, part, NHEAD * KVLR_D, H_DIM, 256);
    reduce_plain<<<160, 256, 0, stream>>>(part, out, 256, (size_t)40960, (size_t)40960);
}

// Round 3
// 538.859 us; speedup vs baseline: 1.7086x; 1.5284x over previous
//
#include <hip/hip_runtime.h>
#include <cmath>

#define B_SZ   8
#define H_DIM  5120
#define NHEAD  128
#define QLR_D  1536
#define ROPE_D 64
#define KVLR_D 512
#define KVLEN  8192
#define SCALE_F 0.07216878364870322f  // 192^-0.5

typedef __attribute__((ext_vector_type(8))) short bf16x8;
typedef __attribute__((ext_vector_type(4))) float f32x4;
typedef __attribute__((ext_vector_type(4))) unsigned short u16x4;

// ws layout (float offsets)
#define WS_CQY    ((size_t)0)          // 12288
#define WS_SSP    ((size_t)12288)      // 64
#define WS_CQ     ((size_t)12352)      // 12288
#define WS_TRIG   ((size_t)24640)      // 524288 (8192*32 float2)
#define WS_QH     ((size_t)548928)     // 294912 float-slots (589824 ushort)
#define WS_QL     ((size_t)843840)     // 294912
#define WS_SCORES ((size_t)1138752)    // 8388608
#define WS_PH     ((size_t)9527360)    // 4194304 float-slots
#define WS_PL     ((size_t)13721664)   // 4194304
#define WS_ATTN   ((size_t)17915968)   // 524288
#define WS_PART   ((size_t)18440256)   // 10485760
#define WS_PART2  ((size_t)28926016)   // 327680

__device__ inline unsigned short f2bf(float x) {
    unsigned int u = __float_as_uint(x);
    u += 0x7FFFu + ((u >> 16) & 1u);
    return (unsigned short)(u >> 16);
}
__device__ inline float bf2f(unsigned short h) {
    return __uint_as_float(((unsigned int)h) << 16);
}

// ---------------- split-K GEMV: C[8,N] = A[8,K] @ B[K,N] ----------------
__global__ __launch_bounds__(256) void gemv8_splitk(
    const float* __restrict__ A, const float* __restrict__ B,
    float* __restrict__ part, int K, int N, int KC)
{
    const int n4 = (blockIdx.x * 256 + threadIdx.x) * 4;
    if (n4 >= N) return;
    const int k0 = blockIdx.y * KC;
    const int kend = min(k0 + KC, K);
    float acc[8][4] = {};
    const float* bp = B + (size_t)k0 * N + n4;
    #pragma unroll 4
    for (int k = k0; k < kend; ++k) {
        const float4 bv = *reinterpret_cast<const float4*>(bp);
        bp += N;
        #pragma unroll
        for (int m = 0; m < 8; ++m) {
            const float av = A[(size_t)m * K + k];
            acc[m][0] = fmaf(av, bv.x, acc[m][0]);
            acc[m][1] = fmaf(av, bv.y, acc[m][1]);
            acc[m][2] = fmaf(av, bv.z, acc[m][2]);
            acc[m][3] = fmaf(av, bv.w, acc[m][3]);
        }
    }
    float* pp = part + (size_t)blockIdx.y * 8 * N;
    #pragma unroll
    for (int m = 0; m < 8; ++m) {
        float4 o; o.x = acc[m][0]; o.y = acc[m][1]; o.z = acc[m][2]; o.w = acc[m][3];
        *reinterpret_cast<float4*>(pp + (size_t)m * N + n4) = o;
    }
}

// ---------------- RMSNorm two-stage ------------------------------------
__global__ __launch_bounds__(256) void rms_stageA(
    const float* __restrict__ part, float* __restrict__ cqy,
    float* __restrict__ ssp, int splits)
{
    const int nb = blockIdx.x, m = blockIdx.y;
    const int n = nb * 256 + threadIdx.x;
    float y = 0.f;
    #pragma unroll 8
    for (int s = 0; s < splits; ++s) y += part[((size_t)s * 8 + m) * QLR_D + n];
    cqy[(size_t)m * QLR_D + n] = y;
    __shared__ float red[256];
    red[threadIdx.x] = y * y; __syncthreads();
    for (int st = 128; st > 0; st >>= 1) {
        if (threadIdx.x < st) red[threadIdx.x] += red[threadIdx.x + st];
        __syncthreads();
    }
    if (threadIdx.x == 0) ssp[m * 6 + nb] = red[0];
}

__global__ __launch_bounds__(256) void rms_stageB(
    const float* __restrict__ cqy, const float* __restrict__ ssp,
    const float* __restrict__ w, float* __restrict__ cq)
{
    const int m = blockIdx.x;
    float ss = 0.f;
    #pragma unroll
    for (int j = 0; j < 6; ++j) ss += ssp[m * 6 + j];
    const float r = 1.0f / sqrtf(ss / (float)QLR_D + 1e-6f);
    for (int n = threadIdx.x; n < QLR_D; n += 256)
        cq[(size_t)m * QLR_D + n] = w[n] * cqy[(size_t)m * QLR_D + n] * r;
}

// ---------------- reduce q_pe partials + RoPE(pos 8191) -> qh/ql --------
__global__ __launch_bounds__(256) void reduce_rope_q(
    const float* __restrict__ part, unsigned short* __restrict__ qh,
    unsigned short* __restrict__ ql, int splits)
{
    const int idx = blockIdx.x * 256 + threadIdx.x;
    if (idx >= B_SZ * NHEAD * 32) return;
    const int p = idx & 31, h = (idx >> 5) & (NHEAD - 1), m = idx >> 12;
    const int N = NHEAD * ROPE_D;
    const int n0 = h * ROPE_D + 2 * p;
    float x0 = 0.f, x1 = 0.f;
    for (int s = 0; s < splits; ++s) {
        const float* pp = part + ((size_t)s * 8 + m) * N + n0;
        x0 += pp[0]; x1 += pp[1];
    }
    const double inv = pow(10000.0, -(double)p / 32.0);
    const float ang = 8191.0f * (float)inv;
    const double c = cos((double)ang), sn = sin((double)ang);
    const float r0 = (float)((double)x0 * c - (double)x1 * sn);
    const float r1 = (float)((double)x0 * sn + (double)x1 * c);
    const size_t o = ((size_t)m * NHEAD + h) * 576 + 2 * p;
    const unsigned short h0 = f2bf(r0), h1 = f2bf(r1);
    qh[o] = h0; qh[o + 1] = h1;
    ql[o] = f2bf(r0 - bf2f(h0)); ql[o + 1] = f2bf(r1 - bf2f(h1));
}

// ---------------- reduce q_nope partials (8 splits) -> qh/ql ------------
__global__ __launch_bounds__(256) void reduce_convert_q(
    const float* __restrict__ part, unsigned short* __restrict__ qh,
    unsigned short* __restrict__ ql)
{
    const int t = blockIdx.x * 256 + threadIdx.x;
    const size_t i4 = (size_t)t * 4;
    if (i4 >= (size_t)B_SZ * NHEAD * 512) return;
    float4 acc = make_float4(0.f, 0.f, 0.f, 0.f);
    #pragma unroll
    for (int s = 0; s < 8; ++s) {
        const float4 v = *reinterpret_cast<const float4*>(part + (size_t)s * 524288 + i4);
        acc.x += v.x; acc.y += v.y; acc.z += v.z; acc.w += v.w;
    }
    const int c = (int)(i4 & 511), bh = (int)(i4 >> 9);
    const size_t o = (size_t)bh * 576 + 64 + c;
    float a[4] = {acc.x, acc.y, acc.z, acc.w};
    u16x4 vh, vl;
    #pragma unroll
    for (int j = 0; j < 4; ++j) {
        const unsigned short hh = f2bf(a[j]);
        vh[j] = hh; vl[j] = f2bf(a[j] - bf2f(hh));
    }
    *reinterpret_cast<u16x4*>(qh + o) = vh;
    *reinterpret_cast<u16x4*>(ql + o) = vl;
}

// ---------------- trig table: [k][p] cos/sin ----------------------------
__global__ __launch_bounds__(256) void trig_table_kernel(float2* __restrict__ tab)
{
    const int idx = blockIdx.x * 256 + threadIdx.x;
    if (idx >= KVLEN * 32) return;
    const int k = idx >> 5, p = idx & 31;
    const double inv = pow(10000.0, -(double)p / 32.0);
    const float ang = (float)k * (float)inv;
    tab[idx] = make_float2((float)cos((double)ang), (float)sin((double)ang));
}

// ---------------- scores via split-bf16 MFMA, dbuf, fused k_pe RoPE -----
// block: 128 heads x 128 keys; grid (64 key-chunks, 8 b); 256 thr = 4 waves
__global__ __launch_bounds__(256) void scores_mfma(
    const unsigned short* __restrict__ qh, const unsigned short* __restrict__ ql,
    const float* __restrict__ kpe, const float* __restrict__ ckv,
    const float2* __restrict__ tab, float* __restrict__ scores)
{
    const int b = blockIdx.y;
    const int k0 = blockIdx.x * 128;
    __shared__ __align__(16) unsigned short kbuf[2][128][64];
    const int tid = threadIdx.x, lane = tid & 63, w = tid >> 6;
    const int hbase = (w >> 1) * 64, kbw = (w & 1) * 64;
    const int skey = tid >> 1, shalf = tid & 1;
    f32x4 acc[4][4] = {};

    float v[16];
    float2 cs[8];
    // prefetch step 0 (c0 = 0, kpe path)
    {
        const float* src = kpe + ((size_t)(b * KVLEN + k0 + skey)) * 64 + shalf * 16;
        #pragma unroll
        for (int q = 0; q < 4; ++q) {
            const float4 f = *reinterpret_cast<const float4*>(src + q * 4);
            v[q*4+0] = f.x; v[q*4+1] = f.y; v[q*4+2] = f.z; v[q*4+3] = f.w;
        }
        const float2* tp = tab + (size_t)(k0 + skey) * 32 + shalf * 8;
        #pragma unroll
        for (int j = 0; j < 8; ++j) cs[j] = tp[j];
    }
    bf16x8 a_hi[4], a_lo[4];
    #pragma unroll
    for (int hs = 0; hs < 4; ++hs) {
        const size_t qoff = ((size_t)(b * NHEAD + hbase + hs * 16 + (lane & 15))) * 576
                            + (lane >> 4) * 8;
        a_hi[hs] = *reinterpret_cast<const bf16x8*>(qh + qoff);
        a_lo[hs] = *reinterpret_cast<const bf16x8*>(ql + qoff);
    }

    for (int s = 0; s < 18; ++s) {
        const int c0 = s * 32;
        // convert current tile (+RoPE for first two steps), write to kbuf[s&1]
        float x[16];
        if (c0 < 64) {
            #pragma unroll
            for (int j = 0; j < 8; ++j) {
                const float x0 = v[2*j], x1 = v[2*j+1];
                x[2*j]   = x0 * cs[j].x - x1 * cs[j].y;
                x[2*j+1] = x0 * cs[j].y + x1 * cs[j].x;
            }
        } else {
            #pragma unroll
            for (int j = 0; j < 16; ++j) x[j] = v[j];
        }
        unsigned short hi[16], lo[16];
        #pragma unroll
        for (int e = 0; e < 16; ++e) {
            hi[e] = f2bf(x[e]);
            lo[e] = f2bf(x[e] - bf2f(hi[e]));
        }
        {
            bf16x8* rowp = reinterpret_cast<bf16x8*>(&kbuf[s & 1][skey][0]);
            const int r7 = skey & 7;
            rowp[(shalf * 2 + 0) ^ r7] = *reinterpret_cast<bf16x8*>(&hi[0]);
            rowp[(shalf * 2 + 1) ^ r7] = *reinterpret_cast<bf16x8*>(&hi[8]);
            rowp[(4 + shalf * 2 + 0) ^ r7] = *reinterpret_cast<bf16x8*>(&lo[0]);
            rowp[(4 + shalf * 2 + 1) ^ r7] = *reinterpret_cast<bf16x8*>(&lo[8]);
        }
        __syncthreads();
        // prefetch step s+1 (hidden under MFMA below)
        bf16x8 na_hi[4], na_lo[4];
        if (s + 1 < 18) {
            const int c1 = c0 + 32;
            if (c1 < 64) {
                const float* src = kpe + ((size_t)(b * KVLEN + k0 + skey)) * 64 + c1 + shalf * 16;
                #pragma unroll
                for (int q = 0; q < 4; ++q) {
                    const float4 f = *reinterpret_cast<const float4*>(src + q * 4);
                    v[q*4+0] = f.x; v[q*4+1] = f.y; v[q*4+2] = f.z; v[q*4+3] = f.w;
                }
                const float2* tp = tab + (size_t)(k0 + skey) * 32 + c1 / 2 + shalf * 8;
                #pragma unroll
                for (int j = 0; j < 8; ++j) cs[j] = tp[j];
            } else {
                const float* src = ckv + ((size_t)(b * KVLEN + k0 + skey)) * 512 + (c1 - 64) + shalf * 16;
                #pragma unroll
                for (int q = 0; q < 4; ++q) {
                    const float4 f = *reinterpret_cast<const float4*>(src + q * 4);
                    v[q*4+0] = f.x; v[q*4+1] = f.y; v[q*4+2] = f.z; v[q*4+3] = f.w;
                }
            }
            #pragma unroll
            for (int hs = 0; hs < 4; ++hs) {
                const size_t qoff = ((size_t)(b * NHEAD + hbase + hs * 16 + (lane & 15))) * 576
                                    + c1 + (lane >> 4) * 8;
                na_hi[hs] = *reinterpret_cast<const bf16x8*>(qh + qoff);
                na_lo[hs] = *reinterpret_cast<const bf16x8*>(ql + qoff);
            }
        }
        // MFMA on current tile
        #pragma unroll
        for (int ks = 0; ks < 4; ++ks) {
            const int row = kbw + ks * 16 + (lane & 15);
            const bf16x8* rp = reinterpret_cast<const bf16x8*>(&kbuf[s & 1][row][0]);
            const int r7 = row & 7;
            const bf16x8 b_hi = rp[(lane >> 4) ^ r7];
            const bf16x8 b_lo = rp[(4 + (lane >> 4)) ^ r7];
            #pragma unroll
            for (int hs = 0; hs < 4; ++hs) {
                acc[hs][ks] = __builtin_amdgcn_mfma_f32_16x16x32_bf16(a_hi[hs], b_hi, acc[hs][ks], 0, 0, 0);
                acc[hs][ks] = __builtin_amdgcn_mfma_f32_16x16x32_bf16(a_hi[hs], b_lo, acc[hs][ks], 0, 0, 0);
                acc[hs][ks] = __builtin_amdgcn_mfma_f32_16x16x32_bf16(a_lo[hs], b_hi, acc[hs][ks], 0, 0, 0);
            }
        }
        if (s + 1 < 18) {
            #pragma unroll
            for (int hs = 0; hs < 4; ++hs) { a_hi[hs] = na_hi[hs]; a_lo[hs] = na_lo[hs]; }
        }
    }
    #pragma unroll
    for (int hs = 0; hs < 4; ++hs)
        #pragma unroll
        for (int ks = 0; ks < 4; ++ks)
            #pragma unroll
            for (int r = 0; r < 4; ++r) {
                const int head = hbase + hs * 16 + (lane >> 4) * 4 + r;
                const int key  = k0 + kbw + ks * 16 + (lane & 15);
                scores[((size_t)(b * NHEAD + head)) * KVLEN + key] = acc[hs][ks][r] * SCALE_F;
            }
}

// ---------------- row softmax over 8192 -> probs hi/lo bf16 -------------
__global__ __launch_bounds__(256) void softmax_kernel(
    const float* __restrict__ sc, unsigned short* __restrict__ ph,
    unsigned short* __restrict__ pl)
{
    const size_t row = (size_t)blockIdx.x * KVLEN;
    const float* p = sc + row;
    const int tid = threadIdx.x;
    float v[32];
    float mx = -3.402823466e38f;
    #pragma unroll
    for (int i = 0; i < 32; ++i) { v[i] = p[i * 256 + tid]; mx = fmaxf(mx, v[i]); }
    #pragma unroll
    for (int off = 32; off >= 1; off >>= 1) mx = fmaxf(mx, __shfl_xor(mx, off, 64));
    __shared__ float red[8];
    if ((tid & 63) == 0) red[tid >> 6] = mx;
    __syncthreads();
    mx = fmaxf(fmaxf(red[0], red[1]), fmaxf(red[2], red[3]));
    float sum = 0.f;
    #pragma unroll
    for (int i = 0; i < 32; ++i) { v[i] = expf(v[i] - mx); sum += v[i]; }
    #pragma unroll
    for (int off = 32; off >= 1; off >>= 1) sum += __shfl_xor(sum, off, 64);
    if ((tid & 63) == 0) red[4 + (tid >> 6)] = sum;
    __syncthreads();
    sum = red[4] + red[5] + red[6] + red[7];
    const float inv = 1.0f / sum;
    #pragma unroll
    for (int i = 0; i < 32; ++i) {
        const float pr = v[i] * inv;
        const unsigned short hi = f2bf(pr);
        ph[row + i * 256 + tid] = hi;
        pl[row + i * 256 + tid] = f2bf(pr - bf2f(hi));
    }
}

// ---------------- PV via split-bf16 MFMA, dbuf, split-K 16 --------------
// block: 128 heads x 128 l, key-chunk 512; grid (4 l-tiles, 16 ks, 8 b)
__global__ __launch_bounds__(256) void pv_mfma(
    const unsigned short* __restrict__ ph, const unsigned short* __restrict__ pl,
    const float* __restrict__ ckv, float* __restrict__ part)
{
    const int lt = blockIdx.x, ks = blockIdx.y, b = blockIdx.z;
    const int l0 = lt * 128;
    __shared__ __align__(16) unsigned short vbuf[2][128][64];
    const int tid = threadIdx.x, lane = tid & 63, w = tid >> 6;
    const int hbase = (w >> 1) * 64, lbw = (w & 1) * 64;
    const int sl = tid & 127, skb = (tid >> 7) * 16;
    f32x4 acc[4][4] = {};
    const int kstart = ks * 512;

    float v[16];
    #pragma unroll
    for (int e = 0; e < 16; ++e)
        v[e] = ckv[((size_t)(b * KVLEN + kstart + skb + e)) * 512 + l0 + sl];
    bf16x8 a_hi[4], a_lo[4];
    #pragma unroll
    for (int hs = 0; hs < 4; ++hs) {
        const size_t poff = ((size_t)(b * NHEAD + hbase + hs * 16 + (lane & 15))) * KVLEN
                            + kstart + (lane >> 4) * 8;
        a_hi[hs] = *reinterpret_cast<const bf16x8*>(ph + poff);
        a_lo[hs] = *reinterpret_cast<const bf16x8*>(pl + poff);
    }

    for (int s = 0; s < 16; ++s) {
        unsigned short hi[16], lo[16];
        #pragma unroll
        for (int e = 0; e < 16; ++e) {
            hi[e] = f2bf(v[e]);
            lo[e] = f2bf(v[e] - bf2f(hi[e]));
        }
        {
            bf16x8* rowp = reinterpret_cast<bf16x8*>(&vbuf[s & 1][sl][0]);
            const int r7 = sl & 7, cb = (tid >> 7) * 2;
            rowp[(cb + 0) ^ r7] = *reinterpret_cast<bf16x8*>(&hi[0]);
            rowp[(cb + 1) ^ r7] = *reinterpret_cast<bf16x8*>(&hi[8]);
            rowp[(4 + cb + 0) ^ r7] = *reinterpret_cast<bf16x8*>(&lo[0]);
            rowp[(4 + cb + 1) ^ r7] = *reinterpret_cast<bf16x8*>(&lo[8]);
        }
        __syncthreads();
        bf16x8 na_hi[4], na_lo[4];
        if (s + 1 < 16) {
            const int kk = kstart + (s + 1) * 32;
            #pragma unroll
            for (int e = 0; e < 16; ++e)
                v[e] = ckv[((size_t)(b * KVLEN + kk + skb + e)) * 512 + l0 + sl];
            #pragma unroll
            for (int hs = 0; hs < 4; ++hs) {
                const size_t poff = ((size_t)(b * NHEAD + hbase + hs * 16 + (lane & 15))) * KVLEN
                                    + kk + (lane >> 4) * 8;
                na_hi[hs] = *reinterpret_cast<const bf16x8*>(ph + poff);
                na_lo[hs] = *reinterpret_cast<const bf16x8*>(pl + poff);
            }
        }
        #pragma unroll
        for (int ls = 0; ls < 4; ++ls) {
            const int row = lbw + ls * 16 + (lane & 15);
            const bf16x8* rp = reinterpret_cast<const bf16x8*>(&vbuf[s & 1][row][0]);
            const int r7 = row & 7;
            const bf16x8 v_hi = rp[(lane >> 4) ^ r7];
            const bf16x8 v_lo = rp[(4 + (lane >> 4)) ^ r7];
            #pragma unroll
            for (int hs = 0; hs < 4; ++hs) {
                acc[hs][ls] = __builtin_amdgcn_mfma_f32_16x16x32_bf16(a_hi[hs], v_hi, acc[hs][ls], 0, 0, 0);
                acc[hs][ls] = __builtin_amdgcn_mfma_f32_16x16x32_bf16(a_hi[hs], v_lo, acc[hs][ls], 0, 0, 0);
                acc[hs][ls] = __builtin_amdgcn_mfma_f32_16x16x32_bf16(a_lo[hs], v_hi, acc[hs][ls], 0, 0, 0);
            }
        }
        if (s + 1 < 16) {
            #pragma unroll
            for (int hs = 0; hs < 4; ++hs) { a_hi[hs] = na_hi[hs]; a_lo[hs] = na_lo[hs]; }
        }
    }
    #pragma unroll
    for (int hs = 0; hs < 4; ++hs)
        #pragma unroll
        for (int ls = 0; ls < 4; ++ls)
            #pragma unroll
            for (int r = 0; r < 4; ++r) {
                const int head = hbase + hs * 16 + (lane >> 4) * 4 + r;
                const int l    = l0 + lbw + ls * 16 + (lane & 15);
                part[(((size_t)ks * B_SZ + b) * NHEAD + head) * KVLR_D + l] = acc[hs][ls][r];
            }
}

// ---------------- attn reduce (16 splits, float4) -----------------------
__global__ __launch_bounds__(256) void reduce_attn(
    const float* __restrict__ part, float* __restrict__ attn)
{
    const int t = blockIdx.x * 256 + threadIdx.x;
    const size_t i4 = (size_t)t * 4;
    if (i4 >= (size_t)524288) return;
    float4 acc = make_float4(0.f, 0.f, 0.f, 0.f);
    #pragma unroll
    for (int s = 0; s < 16; ++s) {
        const float4 v = *reinterpret_cast<const float4*>(part + (size_t)s * 524288 + i4);
        acc.x += v.x; acc.y += v.y; acc.z += v.z; acc.w += v.w;
    }
    *reinterpret_cast<float4*>(attn + i4) = acc;
}

// ---------------- final output reduce, two stages -----------------------
__global__ __launch_bounds__(256) void final_r1(
    const float* __restrict__ part, float* __restrict__ part2)
{
    const int t = blockIdx.x * 256 + threadIdx.x;   // 10240 threads
    const size_t i4 = (size_t)t * 4;
    const int sg = blockIdx.y;
    float4 acc = make_float4(0.f, 0.f, 0.f, 0.f);
    #pragma unroll 8
    for (int s = 0; s < 32; ++s) {
        const float4 v = *reinterpret_cast<const float4*>(
            part + ((size_t)(sg * 32 + s)) * 40960 + i4);
        acc.x += v.x; acc.y += v.y; acc.z += v.z; acc.w += v.w;
    }
    *reinterpret_cast<float4*>(part2 + (size_t)sg * 40960 + i4) = acc;
}

__global__ __launch_bounds__(256) void final_r2(
    const float* __restrict__ part2, float* __restrict__ out)
{
    const int t = blockIdx.x * 256 + threadIdx.x;
    const size_t i4 = (size_t)t * 4;
    float4 acc = make_float4(0.f, 0.f, 0.f, 0.f);
    #pragma unroll
    for (int s = 0; s < 8; ++s) {
        const float4 v = *reinterpret_cast<const float4*>(part2 + (size_t)s * 40960 + i4);
        acc.x += v.x; acc.y += v.y; acc.z += v.z; acc.w += v.w;
    }
    *reinterpret_cast<float4*>(out + i4) = acc;
}

extern "C" void kernel_launch(void* const* d_in, const int* in_sizes, int n_in,
                              void* d_out, int out_size, void* d_ws, size_t ws_size,
                              hipStream_t stream)
{
    const float* hidden  = (const float*)d_in[0];
    const float* ckv     = (const float*)d_in[1];
    const float* kpe     = (const float*)d_in[2];
    const float* W_DQ    = (const float*)d_in[3];
    const float* ln_w    = (const float*)d_in[4];
    const float* W_QR    = (const float*)d_in[5];
    const float* W_UQ_UK = (const float*)d_in[6];
    const float* W_UV_O  = (const float*)d_in[7];
    float* out = (float*)d_out;
    float* ws  = (float*)d_ws;

    float* cqy    = ws + WS_CQY;
    float* ssp    = ws + WS_SSP;
    float* cq     = ws + WS_CQ;
    float2* trig  = (float2*)(ws + WS_TRIG);
    unsigned short* qh = (unsigned short*)(ws + WS_QH);
    unsigned short* ql = (unsigned short*)(ws + WS_QL);
    float* scores = ws + WS_SCORES;
    unsigned short* prh = (unsigned short*)(ws + WS_PH);
    unsigned short* prl = (unsigned short*)(ws + WS_PL);
    float* attn   = ws + WS_ATTN;
    float* part   = ws + WS_PART;
    float* part2  = ws + WS_PART2;

    // trig table first (independent)
    trig_table_kernel<<<1024, 256, 0, stream>>>(trig);
    // 1. cQ = rmsnorm(hidden @ W_DQ)
    gemv8_splitk<<<dim3(2, 80), 256, 0, stream>>>(hidden, W_DQ, part, H_DIM, QLR_D, 64);
    rms_stageA<<<dim3(6, 8), 256, 0, stream>>>(part, cqy, ssp, 80);
    rms_stageB<<<8, 256, 0, stream>>>(cqy, ssp, ln_w, cq);
    // 2. q_pe = rope(cQ @ W_QR) -> qh/ql[0:64]
    gemv8_splitk<<<dim3(8, 32), 256, 0, stream>>>(cq, W_QR, part, QLR_D, NHEAD * ROPE_D, 48);
    reduce_rope_q<<<128, 256, 0, stream>>>(part, qh, ql, 32);
    // 3. q_nope = cQ @ W_UQ_UK -> qh/ql[64:576]
    gemv8_splitk<<<dim3(64, 8), 256, 0, stream>>>(cq, W_UQ_UK, part, QLR_D, NHEAD * KVLR_D, 192);
    reduce_convert_q<<<512, 256, 0, stream>>>(part, qh, ql);
    // 4. scores (fused k_pe RoPE)
    scores_mfma<<<dim3(64, 8), 256, 0, stream>>>(qh, ql, kpe, ckv, trig, scores);
    // 5. softmax -> probs hi/lo
    softmax_kernel<<<1024, 256, 0, stream>>>(scores, prh, prl);
    // 6. attn = probs @ ckv (split-K 16)
    pv_mfma<<<dim3(4, 16, 8), 256, 0, stream>>>(prh, prl, ckv, part);
    reduce_attn<<<512, 256, 0, stream>>>(part, attn);
    // 7. out = attn @ W_UV_O
    gemv8_splitk<<<dim3(5, 256), 256, 0, stream>>>(attn, W_UV_O, part, NHEAD * KVLR_D, H_DIM, 256);
    final_r1<<<dim3(40, 8), 256, 0, stream>>>(part, part2);
    final_r2<<<40, 256, 0, stream>>>(part2, out);
}

// Round 4
// 522.301 us; speedup vs baseline: 1.7628x; 1.0317x over previous
//
#include <hip/hip_runtime.h>
#include <cmath>

#define B_SZ   8
#define H_DIM  5120
#define NHEAD  128
#define QLR_D  1536
#define ROPE_D 64
#define KVLR_D 512
#define KVLEN  8192
#define SCALE_F 0.07216878364870322f  // 192^-0.5

typedef __attribute__((ext_vector_type(8))) short bf16x8;
typedef __attribute__((ext_vector_type(4))) float f32x4;
typedef __attribute__((ext_vector_type(4))) unsigned short u16x4;

// ws layout (float offsets)
#define WS_CQY    ((size_t)0)          // 12288
#define WS_SSP    ((size_t)12288)      // 64
#define WS_CQ     ((size_t)12352)      // 12288
#define WS_TRIG   ((size_t)24640)      // 524288 (8192*32 float2)
#define WS_QH     ((size_t)548928)     // 294912 float-slots (589824 ushort)
#define WS_QL     ((size_t)843840)     // 294912
#define WS_SCORES ((size_t)1138752)    // 8388608
#define WS_PH     ((size_t)9527360)    // 4194304 float-slots
#define WS_ATTN   ((size_t)17915968)   // 524288
#define WS_PART   ((size_t)18440256)   // 10485760
#define WS_PART2  ((size_t)28926016)   // 327680

__device__ inline unsigned short f2bf(float x) {
    unsigned int u = __float_as_uint(x);
    u += 0x7FFFu + ((u >> 16) & 1u);
    return (unsigned short)(u >> 16);
}
__device__ inline float bf2f(unsigned short h) {
    return __uint_as_float(((unsigned int)h) << 16);
}

// ---------------- split-K GEMV: C[8,N] = A[8,K] @ B[K,N] ----------------
__global__ __launch_bounds__(256) void gemv8_splitk(
    const float* __restrict__ A, const float* __restrict__ B,
    float* __restrict__ part, int K, int N, int KC)
{
    const int n4 = (blockIdx.x * 256 + threadIdx.x) * 4;
    if (n4 >= N) return;
    const int k0 = blockIdx.y * KC;
    const int kend = min(k0 + KC, K);
    float acc[8][4] = {};
    const float* bp = B + (size_t)k0 * N + n4;
    #pragma unroll 4
    for (int k = k0; k < kend; ++k) {
        const float4 bv = *reinterpret_cast<const float4*>(bp);
        bp += N;
        #pragma unroll
        for (int m = 0; m < 8; ++m) {
            const float av = A[(size_t)m * K + k];
            acc[m][0] = fmaf(av, bv.x, acc[m][0]);
            acc[m][1] = fmaf(av, bv.y, acc[m][1]);
            acc[m][2] = fmaf(av, bv.z, acc[m][2]);
            acc[m][3] = fmaf(av, bv.w, acc[m][3]);
        }
    }
    float* pp = part + (size_t)blockIdx.y * 8 * N;
    #pragma unroll
    for (int m = 0; m < 8; ++m) {
        float4 o; o.x = acc[m][0]; o.y = acc[m][1]; o.z = acc[m][2]; o.w = acc[m][3];
        *reinterpret_cast<float4*>(pp + (size_t)m * N + n4) = o;
    }
}

// ---------------- RMSNorm two-stage ------------------------------------
__global__ __launch_bounds__(256) void rms_stageA(
    const float* __restrict__ part, float* __restrict__ cqy,
    float* __restrict__ ssp, int splits)
{
    const int nb = blockIdx.x, m = blockIdx.y;
    const int n = nb * 256 + threadIdx.x;
    float y = 0.f;
    #pragma unroll 8
    for (int s = 0; s < splits; ++s) y += part[((size_t)s * 8 + m) * QLR_D + n];
    cqy[(size_t)m * QLR_D + n] = y;
    __shared__ float red[256];
    red[threadIdx.x] = y * y; __syncthreads();
    for (int st = 128; st > 0; st >>= 1) {
        if (threadIdx.x < st) red[threadIdx.x] += red[threadIdx.x + st];
        __syncthreads();
    }
    if (threadIdx.x == 0) ssp[m * 6 + nb] = red[0];
}

__global__ __launch_bounds__(256) void rms_stageB(
    const float* __restrict__ cqy, const float* __restrict__ ssp,
    const float* __restrict__ w, float* __restrict__ cq)
{
    const int m = blockIdx.x;
    float ss = 0.f;
    #pragma unroll
    for (int j = 0; j < 6; ++j) ss += ssp[m * 6 + j];
    const float r = 1.0f / sqrtf(ss / (float)QLR_D + 1e-6f);
    for (int n = threadIdx.x; n < QLR_D; n += 256)
        cq[(size_t)m * QLR_D + n] = w[n] * cqy[(size_t)m * QLR_D + n] * r;
}

// ---------------- reduce q_pe partials + RoPE(pos 8191) -> qh/ql --------
__global__ __launch_bounds__(256) void reduce_rope_q(
    const float* __restrict__ part, unsigned short* __restrict__ qh,
    unsigned short* __restrict__ ql, int splits)
{
    const int idx = blockIdx.x * 256 + threadIdx.x;
    if (idx >= B_SZ * NHEAD * 32) return;
    const int p = idx & 31, h = (idx >> 5) & (NHEAD - 1), m = idx >> 12;
    const int N = NHEAD * ROPE_D;
    const int n0 = h * ROPE_D + 2 * p;
    float x0 = 0.f, x1 = 0.f;
    for (int s = 0; s < splits; ++s) {
        const float* pp = part + ((size_t)s * 8 + m) * N + n0;
        x0 += pp[0]; x1 += pp[1];
    }
    const double inv = pow(10000.0, -(double)p / 32.0);
    const float ang = 8191.0f * (float)inv;
    const double c = cos((double)ang), sn = sin((double)ang);
    const float r0 = (float)((double)x0 * c - (double)x1 * sn);
    const float r1 = (float)((double)x0 * sn + (double)x1 * c);
    const size_t o = ((size_t)m * NHEAD + h) * 576 + 2 * p;
    const unsigned short h0 = f2bf(r0), h1 = f2bf(r1);
    qh[o] = h0; qh[o + 1] = h1;
    ql[o] = f2bf(r0 - bf2f(h0)); ql[o + 1] = f2bf(r1 - bf2f(h1));
}

// ---------------- reduce q_nope partials (4 splits) -> qh/ql ------------
__global__ __launch_bounds__(256) void reduce_convert_q(
    const float* __restrict__ part, unsigned short* __restrict__ qh,
    unsigned short* __restrict__ ql)
{
    const int t = blockIdx.x * 256 + threadIdx.x;
    const size_t i4 = (size_t)t * 4;
    if (i4 >= (size_t)B_SZ * NHEAD * 512) return;
    float4 acc = make_float4(0.f, 0.f, 0.f, 0.f);
    #pragma unroll
    for (int s = 0; s < 4; ++s) {
        const float4 v = *reinterpret_cast<const float4*>(part + (size_t)s * 524288 + i4);
        acc.x += v.x; acc.y += v.y; acc.z += v.z; acc.w += v.w;
    }
    const int c = (int)(i4 & 511), bh = (int)(i4 >> 9);
    const size_t o = (size_t)bh * 576 + 64 + c;
    float a[4] = {acc.x, acc.y, acc.z, acc.w};
    u16x4 vh, vl;
    #pragma unroll
    for (int j = 0; j < 4; ++j) {
        const unsigned short hh = f2bf(a[j]);
        vh[j] = hh; vl[j] = f2bf(a[j] - bf2f(hh));
    }
    *reinterpret_cast<u16x4*>(qh + o) = vh;
    *reinterpret_cast<u16x4*>(ql + o) = vl;
}

// ---------------- trig table: [k][p] cos/sin ----------------------------
__global__ __launch_bounds__(256) void trig_table_kernel(float2* __restrict__ tab)
{
    const int idx = blockIdx.x * 256 + threadIdx.x;
    if (idx >= KVLEN * 32) return;
    const int k = idx >> 5, p = idx & 31;
    const double inv = pow(10000.0, -(double)p / 32.0);
    const float ang = (float)k * (float)inv;
    tab[idx] = make_float2((float)cos((double)ang), (float)sin((double)ang));
}

// ---------------- scores via split-bf16 MFMA, dbuf, fused k_pe RoPE -----
// block: 128 heads x 128 keys; grid (64 key-chunks, 8 b); 256 thr = 4 waves
__global__ __launch_bounds__(256) void scores_mfma(
    const unsigned short* __restrict__ qh, const unsigned short* __restrict__ ql,
    const float* __restrict__ kpe, const float* __restrict__ ckv,
    const float2* __restrict__ tab, float* __restrict__ scores)
{
    const int b = blockIdx.y;
    const int k0 = blockIdx.x * 128;
    __shared__ __align__(16) unsigned short kbuf[2][128][64];
    const int tid = threadIdx.x, lane = tid & 63, w = tid >> 6;
    const int hbase = (w >> 1) * 64, kbw = (w & 1) * 64;
    const int skey = tid >> 1, shalf = tid & 1;
    f32x4 acc[4][4] = {};

    float v[16];
    float2 cs[8];
    // prefetch step 0 (c0 = 0, kpe path)
    {
        const float* src = kpe + ((size_t)(b * KVLEN + k0 + skey)) * 64 + shalf * 16;
        #pragma unroll
        for (int q = 0; q < 4; ++q) {
            const float4 f = *reinterpret_cast<const float4*>(src + q * 4);
            v[q*4+0] = f.x; v[q*4+1] = f.y; v[q*4+2] = f.z; v[q*4+3] = f.w;
        }
        const float2* tp = tab + (size_t)(k0 + skey) * 32 + shalf * 8;
        #pragma unroll
        for (int j = 0; j < 8; ++j) cs[j] = tp[j];
    }
    bf16x8 a_hi[4], a_lo[4];
    #pragma unroll
    for (int hs = 0; hs < 4; ++hs) {
        const size_t qoff = ((size_t)(b * NHEAD + hbase + hs * 16 + (lane & 15))) * 576
                            + (lane >> 4) * 8;
        a_hi[hs] = *reinterpret_cast<const bf16x8*>(qh + qoff);
        a_lo[hs] = *reinterpret_cast<const bf16x8*>(ql + qoff);
    }

    for (int s = 0; s < 18; ++s) {
        const int c0 = s * 32;
        float x[16];
        if (c0 < 64) {
            #pragma unroll
            for (int j = 0; j < 8; ++j) {
                const float x0 = v[2*j], x1 = v[2*j+1];
                x[2*j]   = x0 * cs[j].x - x1 * cs[j].y;
                x[2*j+1] = x0 * cs[j].y + x1 * cs[j].x;
            }
        } else {
            #pragma unroll
            for (int j = 0; j < 16; ++j) x[j] = v[j];
        }
        unsigned short hi[16], lo[16];
        #pragma unroll
        for (int e = 0; e < 16; ++e) {
            hi[e] = f2bf(x[e]);
            lo[e] = f2bf(x[e] - bf2f(hi[e]));
        }
        {
            bf16x8* rowp = reinterpret_cast<bf16x8*>(&kbuf[s & 1][skey][0]);
            const int r7 = skey & 7;
            rowp[(shalf * 2 + 0) ^ r7] = *reinterpret_cast<bf16x8*>(&hi[0]);
            rowp[(shalf * 2 + 1) ^ r7] = *reinterpret_cast<bf16x8*>(&hi[8]);
            rowp[(4 + shalf * 2 + 0) ^ r7] = *reinterpret_cast<bf16x8*>(&lo[0]);
            rowp[(4 + shalf * 2 + 1) ^ r7] = *reinterpret_cast<bf16x8*>(&lo[8]);
        }
        __syncthreads();
        bf16x8 na_hi[4], na_lo[4];
        if (s + 1 < 18) {
            const int c1 = c0 + 32;
            if (c1 < 64) {
                const float* src = kpe + ((size_t)(b * KVLEN + k0 + skey)) * 64 + c1 + shalf * 16;
                #pragma unroll
                for (int q = 0; q < 4; ++q) {
                    const float4 f = *reinterpret_cast<const float4*>(src + q * 4);
                    v[q*4+0] = f.x; v[q*4+1] = f.y; v[q*4+2] = f.z; v[q*4+3] = f.w;
                }
                const float2* tp = tab + (size_t)(k0 + skey) * 32 + c1 / 2 + shalf * 8;
                #pragma unroll
                for (int j = 0; j < 8; ++j) cs[j] = tp[j];
            } else {
                const float* src = ckv + ((size_t)(b * KVLEN + k0 + skey)) * 512 + (c1 - 64) + shalf * 16;
                #pragma unroll
                for (int q = 0; q < 4; ++q) {
                    const float4 f = *reinterpret_cast<const float4*>(src + q * 4);
                    v[q*4+0] = f.x; v[q*4+1] = f.y; v[q*4+2] = f.z; v[q*4+3] = f.w;
                }
            }
            #pragma unroll
            for (int hs = 0; hs < 4; ++hs) {
                const size_t qoff = ((size_t)(b * NHEAD + hbase + hs * 16 + (lane & 15))) * 576
                                    + c1 + (lane >> 4) * 8;
                na_hi[hs] = *reinterpret_cast<const bf16x8*>(qh + qoff);
                na_lo[hs] = *reinterpret_cast<const bf16x8*>(ql + qoff);
            }
        }
        #pragma unroll
        for (int ks = 0; ks < 4; ++ks) {
            const int row = kbw + ks * 16 + (lane & 15);
            const bf16x8* rp = reinterpret_cast<const bf16x8*>(&kbuf[s & 1][row][0]);
            const int r7 = row & 7;
            const bf16x8 b_hi = rp[(lane >> 4) ^ r7];
            const bf16x8 b_lo = rp[(4 + (lane >> 4)) ^ r7];
            #pragma unroll
            for (int hs = 0; hs < 4; ++hs) {
                acc[hs][ks] = __builtin_amdgcn_mfma_f32_16x16x32_bf16(a_hi[hs], b_hi, acc[hs][ks], 0, 0, 0);
                acc[hs][ks] = __builtin_amdgcn_mfma_f32_16x16x32_bf16(a_hi[hs], b_lo, acc[hs][ks], 0, 0, 0);
                acc[hs][ks] = __builtin_amdgcn_mfma_f32_16x16x32_bf16(a_lo[hs], b_hi, acc[hs][ks], 0, 0, 0);
            }
        }
        if (s + 1 < 18) {
            #pragma unroll
            for (int hs = 0; hs < 4; ++hs) { a_hi[hs] = na_hi[hs]; a_lo[hs] = na_lo[hs]; }
        }
    }
    #pragma unroll
    for (int hs = 0; hs < 4; ++hs)
        #pragma unroll
        for (int ks = 0; ks < 4; ++ks)
            #pragma unroll
            for (int r = 0; r < 4; ++r) {
                const int head = hbase + hs * 16 + (lane >> 4) * 4 + r;
                const int key  = k0 + kbw + ks * 16 + (lane & 15);
                scores[((size_t)(b * NHEAD + head)) * KVLEN + key] = acc[hs][ks][r] * SCALE_F;
            }
}

// ---------------- row softmax over 8192 -> probs hi bf16 ----------------
__global__ __launch_bounds__(256) void softmax_kernel(
    const float* __restrict__ sc, unsigned short* __restrict__ ph)
{
    const size_t row = (size_t)blockIdx.x * KVLEN;
    const float* p = sc + row;
    const int tid = threadIdx.x;
    float v[32];
    float mx = -3.402823466e38f;
    #pragma unroll
    for (int i = 0; i < 32; ++i) { v[i] = p[i * 256 + tid]; mx = fmaxf(mx, v[i]); }
    #pragma unroll
    for (int off = 32; off >= 1; off >>= 1) mx = fmaxf(mx, __shfl_xor(mx, off, 64));
    __shared__ float red[8];
    if ((tid & 63) == 0) red[tid >> 6] = mx;
    __syncthreads();
    mx = fmaxf(fmaxf(red[0], red[1]), fmaxf(red[2], red[3]));
    float sum = 0.f;
    #pragma unroll
    for (int i = 0; i < 32; ++i) { v[i] = expf(v[i] - mx); sum += v[i]; }
    #pragma unroll
    for (int off = 32; off >= 1; off >>= 1) sum += __shfl_xor(sum, off, 64);
    if ((tid & 63) == 0) red[4 + (tid >> 6)] = sum;
    __syncthreads();
    sum = red[4] + red[5] + red[6] + red[7];
    const float inv = 1.0f / sum;
    #pragma unroll
    for (int i = 0; i < 32; ++i)
        ph[row + i * 256 + tid] = f2bf(v[i] * inv);
}

// ---------------- PV via bf16 MFMA (probs hi x V hi/lo), dbuf -----------
// block: 128 heads x 256 l, key-chunk 512; grid (2 l-tiles, 16 ks, 8 b) = 256
__global__ __launch_bounds__(256, 1) void pv_mfma(
    const unsigned short* __restrict__ ph,
    const float* __restrict__ ckv, float* __restrict__ part)
{
    const int lt = blockIdx.x, ks = blockIdx.y, b = blockIdx.z;
    const int l0 = lt * 256;
    __shared__ __align__(16) unsigned short vbuf[2][256][64];   // 64 KiB
    const int tid = threadIdx.x, lane = tid & 63, w = tid >> 6;
    const int hbase = (w >> 1) * 64, lbw = (w & 1) * 128;
    const int lq = (tid & 63) * 4;       // l column group (4 floats)
    const int kb = (tid >> 6) * 8;       // 8 k rows per thread
    f32x4 acc[4][8] = {};
    const int kstart = ks * 512;

    float4 v4[8];
    #pragma unroll
    for (int e = 0; e < 8; ++e)
        v4[e] = *reinterpret_cast<const float4*>(
            ckv + ((size_t)(b * KVLEN + kstart + kb + e)) * 512 + l0 + lq);
    bf16x8 a_hi[4];
    #pragma unroll
    for (int hs = 0; hs < 4; ++hs) {
        const size_t poff = ((size_t)(b * NHEAD + hbase + hs * 16 + (lane & 15))) * KVLEN
                            + kstart + (lane >> 4) * 8;
        a_hi[hs] = *reinterpret_cast<const bf16x8*>(ph + poff);
    }

    for (int s = 0; s < 16; ++s) {
        // convert current 8k x 4l block and write to LDS rows l = lq..lq+3
        const float vv[8][4] = {
            {v4[0].x, v4[0].y, v4[0].z, v4[0].w}, {v4[1].x, v4[1].y, v4[1].z, v4[1].w},
            {v4[2].x, v4[2].y, v4[2].z, v4[2].w}, {v4[3].x, v4[3].y, v4[3].z, v4[3].w},
            {v4[4].x, v4[4].y, v4[4].z, v4[4].w}, {v4[5].x, v4[5].y, v4[5].z, v4[5].w},
            {v4[6].x, v4[6].y, v4[6].z, v4[6].w}, {v4[7].x, v4[7].y, v4[7].z, v4[7].w}};
        #pragma unroll
        for (int j = 0; j < 4; ++j) {
            bf16x8 h8, l8;
            #pragma unroll
            for (int e = 0; e < 8; ++e) {
                const float x = vv[e][j];
                const unsigned short hh = f2bf(x);
                h8[e] = (short)hh;
                l8[e] = (short)f2bf(x - bf2f(hh));
            }
            const int row = lq + j, r7 = row & 7;
            bf16x8* rowp = reinterpret_cast<bf16x8*>(&vbuf[s & 1][row][0]);
            rowp[(kb >> 3) ^ r7] = h8;
            rowp[(4 + (kb >> 3)) ^ r7] = l8;
        }
        __syncthreads();
        bf16x8 na_hi[4];
        if (s + 1 < 16) {
            const int kk = kstart + (s + 1) * 32;
            #pragma unroll
            for (int e = 0; e < 8; ++e)
                v4[e] = *reinterpret_cast<const float4*>(
                    ckv + ((size_t)(b * KVLEN + kk + kb + e)) * 512 + l0 + lq);
            #pragma unroll
            for (int hs = 0; hs < 4; ++hs) {
                const size_t poff = ((size_t)(b * NHEAD + hbase + hs * 16 + (lane & 15))) * KVLEN
                                    + kk + (lane >> 4) * 8;
                na_hi[hs] = *reinterpret_cast<const bf16x8*>(ph + poff);
            }
        }
        #pragma unroll
        for (int ls = 0; ls < 8; ++ls) {
            const int row = lbw + ls * 16 + (lane & 15);
            const bf16x8* rp = reinterpret_cast<const bf16x8*>(&vbuf[s & 1][row][0]);
            const int r7 = row & 7;
            const bf16x8 v_hi = rp[(lane >> 4) ^ r7];
            const bf16x8 v_lo = rp[(4 + (lane >> 4)) ^ r7];
            #pragma unroll
            for (int hs = 0; hs < 4; ++hs) {
                acc[hs][ls] = __builtin_amdgcn_mfma_f32_16x16x32_bf16(a_hi[hs], v_hi, acc[hs][ls], 0, 0, 0);
                acc[hs][ls] = __builtin_amdgcn_mfma_f32_16x16x32_bf16(a_hi[hs], v_lo, acc[hs][ls], 0, 0, 0);
            }
        }
        if (s + 1 < 16) {
            #pragma unroll
            for (int hs = 0; hs < 4; ++hs) a_hi[hs] = na_hi[hs];
        }
    }
    #pragma unroll
    for (int hs = 0; hs < 4; ++hs)
        #pragma unroll
        for (int ls = 0; ls < 8; ++ls)
            #pragma unroll
            for (int r = 0; r < 4; ++r) {
                const int head = hbase + hs * 16 + (lane >> 4) * 4 + r;
                const int l    = l0 + lbw + ls * 16 + (lane & 15);
                part[(((size_t)ks * B_SZ + b) * NHEAD + head) * KVLR_D + l] = acc[hs][ls][r];
            }
}

// ---------------- attn reduce (16 splits, float4) -----------------------
__global__ __launch_bounds__(256) void reduce_attn(
    const float* __restrict__ part, float* __restrict__ attn)
{
    const int t = blockIdx.x * 256 + threadIdx.x;
    const size_t i4 = (size_t)t * 4;
    if (i4 >= (size_t)524288) return;
    float4 acc = make_float4(0.f, 0.f, 0.f, 0.f);
    #pragma unroll
    for (int s = 0; s < 16; ++s) {
        const float4 v = *reinterpret_cast<const float4*>(part + (size_t)s * 524288 + i4);
        acc.x += v.x; acc.y += v.y; acc.z += v.z; acc.w += v.w;
    }
    *reinterpret_cast<float4*>(attn + i4) = acc;
}

// ---------------- final output reduce, two stages -----------------------
__global__ __launch_bounds__(256) void final_r1(
    const float* __restrict__ part, float* __restrict__ part2)
{
    const int t = blockIdx.x * 256 + threadIdx.x;   // 10240 threads
    const size_t i4 = (size_t)t * 4;
    const int sg = blockIdx.y;
    float4 acc = make_float4(0.f, 0.f, 0.f, 0.f);
    #pragma unroll 8
    for (int s = 0; s < 32; ++s) {
        const float4 v = *reinterpret_cast<const float4*>(
            part + ((size_t)(sg * 32 + s)) * 40960 + i4);
        acc.x += v.x; acc.y += v.y; acc.z += v.z; acc.w += v.w;
    }
    *reinterpret_cast<float4*>(part2 + (size_t)sg * 40960 + i4) = acc;
}

__global__ __launch_bounds__(256) void final_r2(
    const float* __restrict__ part2, float* __restrict__ out)
{
    const int t = blockIdx.x * 256 + threadIdx.x;
    const size_t i4 = (size_t)t * 4;
    float4 acc = make_float4(0.f, 0.f, 0.f, 0.f);
    #pragma unroll
    for (int s = 0; s < 4; ++s) {
        const float4 v = *reinterpret_cast<const float4*>(part2 + (size_t)s * 40960 + i4);
        acc.x += v.x; acc.y += v.y; acc.z += v.z; acc.w += v.w;
    }
    *reinterpret_cast<float4*>(out + i4) = acc;
}

extern "C" void kernel_launch(void* const* d_in, const int* in_sizes, int n_in,
                              void* d_out, int out_size, void* d_ws, size_t ws_size,
                              hipStream_t stream)
{
    const float* hidden  = (const float*)d_in[0];
    const float* ckv     = (const float*)d_in[1];
    const float* kpe     = (const float*)d_in[2];
    const float* W_DQ    = (const float*)d_in[3];
    const float* ln_w    = (const float*)d_in[4];
    const float* W_QR    = (const float*)d_in[5];
    const float* W_UQ_UK = (const float*)d_in[6];
    const float* W_UV_O  = (const float*)d_in[7];
    float* out = (float*)d_out;
    float* ws  = (float*)d_ws;

    float* cqy    = ws + WS_CQY;
    float* ssp    = ws + WS_SSP;
    float* cq     = ws + WS_CQ;
    float2* trig  = (float2*)(ws + WS_TRIG);
    unsigned short* qh = (unsigned short*)(ws + WS_QH);
    unsigned short* ql = (unsigned short*)(ws + WS_QL);
    float* scores = ws + WS_SCORES;
    unsigned short* prh = (unsigned short*)(ws + WS_PH);
    float* attn   = ws + WS_ATTN;
    float* part   = ws + WS_PART;
    float* part2  = ws + WS_PART2;

    // trig table first (independent)
    trig_table_kernel<<<1024, 256, 0, stream>>>(trig);
    // 1. cQ = rmsnorm(hidden @ W_DQ)
    gemv8_splitk<<<dim3(2, 80), 256, 0, stream>>>(hidden, W_DQ, part, H_DIM, QLR_D, 64);
    rms_stageA<<<dim3(6, 8), 256, 0, stream>>>(part, cqy, ssp, 80);
    rms_stageB<<<8, 256, 0, stream>>>(cqy, ssp, ln_w, cq);
    // 2. q_pe = rope(cQ @ W_QR) -> qh/ql[0:64]
    gemv8_splitk<<<dim3(8, 32), 256, 0, stream>>>(cq, W_QR, part, QLR_D, NHEAD * ROPE_D, 48);
    reduce_rope_q<<<128, 256, 0, stream>>>(part, qh, ql, 32);
    // 3. q_nope = cQ @ W_UQ_UK -> qh/ql[64:576]  (4 splits)
    gemv8_splitk<<<dim3(64, 4), 256, 0, stream>>>(cq, W_UQ_UK, part, QLR_D, NHEAD * KVLR_D, 384);
    reduce_convert_q<<<512, 256, 0, stream>>>(part, qh, ql);
    // 4. scores (fused k_pe RoPE)
    scores_mfma<<<dim3(64, 8), 256, 0, stream>>>(qh, ql, kpe, ckv, trig, scores);
    // 5. softmax -> probs hi
    softmax_kernel<<<1024, 256, 0, stream>>>(scores, prh);
    // 6. attn = probs @ ckv (split-K 16, 2 l-tiles)
    pv_mfma<<<dim3(2, 16, 8), 256, 0, stream>>>(prh, ckv, part);
    reduce_attn<<<512, 256, 0, stream>>>(part, attn);
    // 7. out = attn @ W_UV_O (128 splits)
    gemv8_splitk<<<dim3(5, 128), 256, 0, stream>>>(attn, W_UV_O, part, NHEAD * KVLR_D, H_DIM, 512);
    final_r1<<<dim3(40, 4), 256, 0, stream>>>(part, part2);
    final_r2<<<40, 256, 0, stream>>>(part2, out);
}